// Round 1
// baseline (226.726 us; speedup 1.0000x reference)
//
#include <hip/hip_runtime.h>
#include <hip/hip_bf16.h>

#define N_NODES 100000
#define N_EDGES 1600000
#define D_IN    128
#define D_HID   16
#define D_OUT   32

// ---------------------------------------------------------------------------
// Kernel 1: Y = features @ W1   (N_NODES x 128) @ (128 x 16) -> (N_NODES x 16)
// thread per (node, j). W1 (8 KB) staged in LDS.
// ---------------------------------------------------------------------------
__global__ void k_mm1(const float* __restrict__ feat,
                      const float* __restrict__ W1,
                      float* __restrict__ Y) {
    __shared__ float sW[D_IN * D_HID];  // 2048 floats = 8 KB
    for (int i = threadIdx.x; i < D_IN * D_HID; i += blockDim.x)
        sW[i] = W1[i];
    __syncthreads();

    int gid = blockIdx.x * blockDim.x + threadIdx.x;
    if (gid >= N_NODES * D_HID) return;
    int n = gid >> 4;       // node
    int j = gid & 15;       // hidden channel

    const float* frow = feat + (size_t)n * D_IN;
    float acc = 0.f;
#pragma unroll 8
    for (int k = 0; k < D_IN; ++k)
        acc = fmaf(frow[k], sW[k * D_HID + j], acc);
    Y[gid] = acc;
}

// ---------------------------------------------------------------------------
// Kernel 2: scatter-add  agg[dst[e]][j] += val[src[e]][j]   (j = 0..15)
// 16 consecutive lanes handle one edge -> 64B coalesced gather per edge.
// ---------------------------------------------------------------------------
__global__ void k_scatter(const float* __restrict__ val,
                          const int* __restrict__ src,
                          const int* __restrict__ dst,
                          float* __restrict__ agg) {
    int gid = blockIdx.x * blockDim.x + threadIdx.x;
    if (gid >= N_EDGES * D_HID) return;
    int e = gid >> 4;
    int j = gid & 15;
    int s = src[e];
    int d = dst[e];
    atomicAdd(&agg[(size_t)d * D_HID + j], val[(size_t)s * D_HID + j]);
}

// ---------------------------------------------------------------------------
// Kernel 3: scatter-add with fused bias+ReLU on the gathered value:
//   h = relu(agg1[src[e]][j] + b1[j]);  agg2[dst[e]][j] += h
// ---------------------------------------------------------------------------
__global__ void k_scatter_relu(const float* __restrict__ agg1,
                               const float* __restrict__ b1,
                               const int* __restrict__ src,
                               const int* __restrict__ dst,
                               float* __restrict__ agg2) {
    int gid = blockIdx.x * blockDim.x + threadIdx.x;
    if (gid >= N_EDGES * D_HID) return;
    int e = gid >> 4;
    int j = gid & 15;
    int s = src[e];
    int d = dst[e];
    float h = agg1[(size_t)s * D_HID + j] + b1[j];
    h = h > 0.f ? h : 0.f;
    atomicAdd(&agg2[(size_t)d * D_HID + j], h);
}

// ---------------------------------------------------------------------------
// Kernel 4: out = agg2 @ W2 + b2   (N x 16) @ (16 x 32) -> (N x 32)
// thread per (node, o); W2 (2 KB) is L1-resident, read directly.
// ---------------------------------------------------------------------------
__global__ void k_mm2(const float* __restrict__ agg2,
                      const float* __restrict__ W2,
                      const float* __restrict__ b2,
                      float* __restrict__ out) {
    int gid = blockIdx.x * blockDim.x + threadIdx.x;
    if (gid >= N_NODES * D_OUT) return;
    int n = gid >> 5;
    int o = gid & 31;
    const float* arow = agg2 + (size_t)n * D_HID;
    float acc = b2[o];
#pragma unroll
    for (int j = 0; j < D_HID; ++j)
        acc = fmaf(arow[j], W2[j * D_OUT + o], acc);
    out[gid] = acc;
}

// ---------------------------------------------------------------------------
extern "C" void kernel_launch(void* const* d_in, const int* in_sizes, int n_in,
                              void* d_out, int out_size, void* d_ws, size_t ws_size,
                              hipStream_t stream) {
    const float* feat = (const float*)d_in[0];
    const int*   src  = (const int*)d_in[1];
    const int*   dst  = (const int*)d_in[2];
    const float* W1   = (const float*)d_in[3];
    const float* b1   = (const float*)d_in[4];
    const float* W2   = (const float*)d_in[5];
    const float* b2   = (const float*)d_in[6];
    float* out = (float*)d_out;

    // workspace layout (all fp32):
    //   Y    : N_NODES*16  @ offset 0          (6.4 MB)
    //   agg1 : N_NODES*16  @ offset 6.4 MB     (6.4 MB)
    //   agg2 : N_NODES*16  @ offset 12.8 MB    (6.4 MB)
    char* base = (char*)d_ws;
    const size_t SZ = (size_t)N_NODES * D_HID * sizeof(float);  // 6,400,000 B
    float* Y    = (float*)(base);
    float* agg1 = (float*)(base + SZ);
    float* agg2 = (float*)(base + 2 * SZ);

    // zero the two accumulators every call (ws is poisoned / stale otherwise)
    hipMemsetAsync(agg1, 0, 2 * SZ, stream);

    const int BLK = 256;

    // 1) Y = feat @ W1
    {
        int total = N_NODES * D_HID;
        k_mm1<<<(total + BLK - 1) / BLK, BLK, 0, stream>>>(feat, W1, Y);
    }
    // 2) agg1[dst] += Y[src]
    {
        int total = N_EDGES * D_HID;
        k_scatter<<<(total + BLK - 1) / BLK, BLK, 0, stream>>>(Y, src, dst, agg1);
    }
    // 3) agg2[dst] += relu(agg1[src] + b1)
    {
        int total = N_EDGES * D_HID;
        k_scatter_relu<<<(total + BLK - 1) / BLK, BLK, 0, stream>>>(agg1, b1, src, dst, agg2);
    }
    // 4) out = agg2 @ W2 + b2
    {
        int total = N_NODES * D_OUT;
        k_mm2<<<(total + BLK - 1) / BLK, BLK, 0, stream>>>(agg2, W2, b2, out);
    }
}